// Round 11
// baseline (180.110 us; speedup 1.0000x reference)
//
#include <hip/hip_runtime.h>
#include <hip/hip_bf16.h>
#include <hip/hip_cooperative_groups.h>

namespace cg = cooperative_groups;

#define N_NODES 20000
#define N_EDGES 150000
#define D 512
#define MPAD 20096   // 157 * 128
#define BN_EPS 1e-5f

typedef __attribute__((ext_vector_type(8))) short s16x8;
typedef __attribute__((ext_vector_type(4))) float f32x4;

__device__ __forceinline__ short f2bf(float f) {
    union { float f; unsigned u; } v; v.f = f;
    unsigned r = (v.u + 0x7fff + ((v.u >> 16) & 1)) >> 16;
    return (short)r;
}
__device__ __forceinline__ float bf2f(short b) {
    union { unsigned u; float f; } c;
    c.u = ((unsigned)(unsigned short)b) << 16;
    return c.f;
}
__device__ __forceinline__ s16x8 cvt8(const float* p) {
    float4 a = *(const float4*)p;
    float4 b = *(const float4*)(p + 4);
    s16x8 o;
    o[0] = f2bf(a.x); o[1] = f2bf(a.y); o[2] = f2bf(a.z); o[3] = f2bf(a.w);
    o[4] = f2bf(b.x); o[5] = f2bf(b.y); o[6] = f2bf(b.z); o[7] = f2bf(b.w);
    return o;
}

__device__ __forceinline__ void load_lds16(const short* g, short* l) {
    __builtin_amdgcn_global_load_lds((const __attribute__((address_space(1))) void*)g,
                                     (__attribute__((address_space(3))) void*)l, 16, 0, 0);
}

// ================= K1: W/X -> bf16 conversion + zero count array =================
#define WCH (D * D / 8)
#define XCH (N_NODES * D / 8)
#define CONVCH (WCH + XCH)
#define ZCH 5120
__global__ __launch_bounds__(256) void convert_wx_zero(const float* __restrict__ W,
                                                       const float* __restrict__ x,
                                                       short* __restrict__ Wb,
                                                       short* __restrict__ Xb,
                                                       int* __restrict__ count) {
    int c = blockIdx.x * 256 + threadIdx.x;
    if (c < WCH) {
        *(s16x8*)(Wb + (size_t)c * 8) = cvt8(W + (size_t)c * 8);
    } else if (c < CONVCH) {
        size_t idx = (size_t)(c - WCH) * 8;
        *(s16x8*)(Xb + idx) = cvt8(x + idx);
    } else {
        int z = c - CONVCH;
        if (z * 4 < N_NODES) *(int4*)(count + z * 4) = make_int4(0, 0, 0, 0);
    }
}

// ================= K2: count in-degrees =================
__global__ __launch_bounds__(256) void count_edges(const int* __restrict__ dst,
                                                   int* __restrict__ count) {
    int i = blockIdx.x * 256 + threadIdx.x;
    if (i * 8 < N_EDGES) {
        int4 a = *(const int4*)(dst + i * 8);
        int4 b = *(const int4*)(dst + i * 8 + 4);
        atomicAdd(&count[a.x], 1); atomicAdd(&count[a.y], 1);
        atomicAdd(&count[a.z], 1); atomicAdd(&count[a.w], 1);
        atomicAdd(&count[b.x], 1); atomicAdd(&count[b.y], 1);
        atomicAdd(&count[b.z], 1); atomicAdd(&count[b.w], 1);
    }
}

// ================= K3: scan (1 block, vectorized, reg prefix) =================
__global__ __launch_bounds__(1024) void scan_csr(const int* __restrict__ count,
                                                 int* __restrict__ rowstart,
                                                 int* __restrict__ cursor,
                                                 float* __restrict__ colsum,
                                                 float* __restrict__ colsumsq) {
    __shared__ int partial[1024];
    int t = threadIdx.x;
    if (t < D) colsum[t] = 0.f;
    else if (t < 2 * D) colsumsq[t - D] = 0.f;

    int v[20];
    int s = 0;
    if (t < 1000) {
        const int4* p = (const int4*)(count + t * 20);
        #pragma unroll
        for (int j = 0; j < 5; ++j) {
            int4 q = p[j];
            v[j * 4 + 0] = q.x; v[j * 4 + 1] = q.y;
            v[j * 4 + 2] = q.z; v[j * 4 + 3] = q.w;
        }
        #pragma unroll
        for (int j = 0; j < 20; ++j) s += v[j];
    }
    partial[t] = s;
    __syncthreads();
    for (int off = 1; off < 1024; off <<= 1) {
        int p2 = (t >= off) ? partial[t - off] : 0;
        __syncthreads();
        partial[t] += p2;
        __syncthreads();
    }
    if (t < 1000) {
        int run = (t == 0) ? 0 : partial[t - 1];
        int rs[20];
        #pragma unroll
        for (int j = 0; j < 20; ++j) { rs[j] = run; run += v[j]; }
        int4* rp = (int4*)(rowstart + t * 20);
        int4* cp = (int4*)(cursor + t * 20);
        #pragma unroll
        for (int j = 0; j < 5; ++j) {
            int4 q = make_int4(rs[j * 4], rs[j * 4 + 1], rs[j * 4 + 2], rs[j * 4 + 3]);
            rp[j] = q;
            cp[j] = q;
        }
    }
    if (t == 1023) rowstart[N_NODES] = partial[1023];
}

// ================= K4: fill sorted edge list =================
__global__ __launch_bounds__(256) void fill_edges(const int* __restrict__ src,
                                                  const int* __restrict__ dst,
                                                  int* __restrict__ cursor,
                                                  int* __restrict__ esrc) {
    int i = blockIdx.x * 256 + threadIdx.x;
    if (i < N_EDGES) {
        int p = atomicAdd(&cursor[dst[i]], 1);
        esrc[p] = src[i];
    }
}

// ================= K5: gather, 4 independent accumulator banks =================
__global__ __launch_bounds__(256) void gather_bf16(const short* __restrict__ Xb,
                                                   const int* __restrict__ rowstart,
                                                   const int* __restrict__ esrc,
                                                   short* __restrict__ Ab) {
    int node = (blockIdx.x * 256 + threadIdx.x) >> 6;
    int lane = threadIdx.x & 63;
    if (node >= MPAD) return;
    size_t cb = (size_t)lane * 8;
    s16x8 o;
    if (node >= N_NODES) {
        o = (s16x8)0;
    } else {
        int e0 = rowstart[node], e1 = rowstart[node + 1];
        if (e0 == e1) {
            o = *(const s16x8*)(Xb + (size_t)node * D + cb);
        } else {
            float a0[8] = {}, a1[8] = {}, a2[8] = {}, a3[8] = {};
            int e = e0;
            for (; e + 3 < e1; e += 4) {
                int s0 = esrc[e], s1 = esrc[e + 1], s2 = esrc[e + 2], s3 = esrc[e + 3];
                s16x8 v0 = *(const s16x8*)(Xb + (size_t)s0 * D + cb);
                s16x8 v1 = *(const s16x8*)(Xb + (size_t)s1 * D + cb);
                s16x8 v2 = *(const s16x8*)(Xb + (size_t)s2 * D + cb);
                s16x8 v3 = *(const s16x8*)(Xb + (size_t)s3 * D + cb);
                #pragma unroll
                for (int i = 0; i < 8; ++i) a0[i] += bf2f(v0[i]);
                #pragma unroll
                for (int i = 0; i < 8; ++i) a1[i] += bf2f(v1[i]);
                #pragma unroll
                for (int i = 0; i < 8; ++i) a2[i] += bf2f(v2[i]);
                #pragma unroll
                for (int i = 0; i < 8; ++i) a3[i] += bf2f(v3[i]);
            }
            if (e < e1) {
                s16x8 v0 = *(const s16x8*)(Xb + (size_t)esrc[e] * D + cb);
                #pragma unroll
                for (int i = 0; i < 8; ++i) a0[i] += bf2f(v0[i]);
            }
            if (e + 1 < e1) {
                s16x8 v1 = *(const s16x8*)(Xb + (size_t)esrc[e + 1] * D + cb);
                #pragma unroll
                for (int i = 0; i < 8; ++i) a1[i] += bf2f(v1[i]);
            }
            if (e + 2 < e1) {
                s16x8 v2 = *(const s16x8*)(Xb + (size_t)esrc[e + 2] * D + cb);
                #pragma unroll
                for (int i = 0; i < 8; ++i) a2[i] += bf2f(v2[i]);
            }
            #pragma unroll
            for (int i = 0; i < 8; ++i) o[i] = f2bf((a0[i] + a1[i]) + (a2[i] + a3[i]));
        }
    }
    *(s16x8*)(Ab + (size_t)node * D + cb) = o;
}

// ================= GEMM tile params =================
#define BM 128
#define BNT 128
#define BK 32

// ================= K6 (cooperative): GEMM + ReLU + stats + grid.sync + BN, f32 out =================
__global__ __launch_bounds__(256) void gemm_bn_fused(const short* __restrict__ A,
                                                     const short* __restrict__ B,
                                                     const float* __restrict__ bias,
                                                     float* __restrict__ out,
                                                     float* __restrict__ colsum,
                                                     float* __restrict__ colsumsq,
                                                     const float* __restrict__ gamma,
                                                     const float* __restrict__ beta) {
    __shared__ short As[BM * BK];
    __shared__ short Bs[BNT * BK];
    __shared__ float s_scale[BNT], s_shift[BNT];
    int tid = threadIdx.x;
    int lane = tid & 63;
    int wave = tid >> 6;
    int wr = wave >> 1, wc = wave & 1;
    int m0 = blockIdx.x * BM;
    int n0 = blockIdx.y * BNT;

    f32x4 acc[4][4] = {};

    int srow = lane >> 2;
    int scol = (lane & 3) * 8;
    const short* Ag = A + (size_t)(m0 + wave * 32 + srow) * D + scol;
    const short* Bg = B + (size_t)(n0 + wave * 32 + srow) * D + scol;
    short* Asl = As + wave * 1024;
    short* Bsl = Bs + wave * 1024;

    for (int kt = 0; kt < D; kt += BK) {
        #pragma unroll
        for (int j = 0; j < 2; ++j) {
            load_lds16(Ag + (size_t)j * 16 * D + kt, Asl + j * 512);
            load_lds16(Bg + (size_t)j * 16 * D + kt, Bsl + j * 512);
        }
        __syncthreads();
        s16x8 af[4], bfr[4];
        int ko = (lane >> 4) * 8;
        #pragma unroll
        for (int m = 0; m < 4; ++m)
            af[m] = *(const s16x8*)(As + (wr * 64 + m * 16 + (lane & 15)) * BK + ko);
        #pragma unroll
        for (int n = 0; n < 4; ++n)
            bfr[n] = *(const s16x8*)(Bs + (wc * 64 + n * 16 + (lane & 15)) * BK + ko);
        #pragma unroll
        for (int m = 0; m < 4; ++m)
            #pragma unroll
            for (int n = 0; n < 4; ++n)
                acc[m][n] = __builtin_amdgcn_mfma_f32_16x16x32_bf16(af[m], bfr[n], acc[m][n], 0, 0, 0);
        __syncthreads();
    }

    // epilogue: bias + relu in registers, column stats
    #pragma unroll
    for (int n = 0; n < 4; ++n) {
        int col = n0 + wc * 64 + n * 16 + (lane & 15);
        float bv = bias[col];
        float s = 0.f, q = 0.f;
        #pragma unroll
        for (int m = 0; m < 4; ++m) {
            int rbase = m0 + wr * 64 + m * 16 + (lane >> 4) * 4;
            #pragma unroll
            for (int r = 0; r < 4; ++r) {
                float v = acc[m][n][r] + bv;
                v = v > 0.f ? v : 0.f;
                acc[m][n][r] = v;
                if (rbase + r < N_NODES) { s += v; q += v * v; }
            }
        }
        s += __shfl_xor(s, 16, 64);
        s += __shfl_xor(s, 32, 64);
        q += __shfl_xor(q, 16, 64);
        q += __shfl_xor(q, 32, 64);
        if (lane < 16) {
            atomicAdd(&colsum[col], s);
            atomicAdd(&colsumsq[col], q);
        }
    }

    cg::this_grid().sync();

    // BN params for this block's 128 columns (device-scope loads: cross-XCD safety)
    if (tid < BNT) {
        int c = n0 + tid;
        float cs = __hip_atomic_load(&colsum[c], __ATOMIC_RELAXED, __HIP_MEMORY_SCOPE_AGENT);
        float cq = __hip_atomic_load(&colsumsq[c], __ATOMIC_RELAXED, __HIP_MEMORY_SCOPE_AGENT);
        float mean = cs * (1.f / N_NODES);
        float var = cq * (1.f / N_NODES) - mean * mean;
        float rs = rsqrtf(var + BN_EPS);
        float sc = gamma[c] * rs;
        s_scale[tid] = sc;
        s_shift[tid] = beta[c] - mean * sc;
    }
    __syncthreads();

    #pragma unroll
    for (int n = 0; n < 4; ++n) {
        int lcol = wc * 64 + n * 16 + (lane & 15);
        float sc = s_scale[lcol], sh = s_shift[lcol];
        int col = n0 + lcol;
        #pragma unroll
        for (int m = 0; m < 4; ++m) {
            int rbase = m0 + wr * 64 + m * 16 + (lane >> 4) * 4;
            #pragma unroll
            for (int r = 0; r < 4; ++r) {
                int row = rbase + r;
                if (row < N_NODES) out[(size_t)row * D + col] = acc[m][n][r] * sc + sh;
            }
        }
    }
}

// ================= Fallback K6: GEMM h = relu(A@W^T+b) bf16, fused stats =================
__global__ __launch_bounds__(256) void gemm_relu_stats(const short* __restrict__ A,
                                                       const short* __restrict__ B,
                                                       const float* __restrict__ bias,
                                                       short* __restrict__ h,
                                                       float* __restrict__ colsum,
                                                       float* __restrict__ colsumsq) {
    __shared__ short As[BM * BK];
    __shared__ short Bs[BNT * BK];
    int tid = threadIdx.x;
    int lane = tid & 63;
    int wave = tid >> 6;
    int wr = wave >> 1, wc = wave & 1;
    int m0 = blockIdx.x * BM;
    int n0 = blockIdx.y * BNT;

    f32x4 acc[4][4] = {};

    int srow = lane >> 2;
    int scol = (lane & 3) * 8;
    const short* Ag = A + (size_t)(m0 + wave * 32 + srow) * D + scol;
    const short* Bg = B + (size_t)(n0 + wave * 32 + srow) * D + scol;
    short* Asl = As + wave * 1024;
    short* Bsl = Bs + wave * 1024;

    for (int kt = 0; kt < D; kt += BK) {
        #pragma unroll
        for (int j = 0; j < 2; ++j) {
            load_lds16(Ag + (size_t)j * 16 * D + kt, Asl + j * 512);
            load_lds16(Bg + (size_t)j * 16 * D + kt, Bsl + j * 512);
        }
        __syncthreads();
        s16x8 af[4], bfr[4];
        int ko = (lane >> 4) * 8;
        #pragma unroll
        for (int m = 0; m < 4; ++m)
            af[m] = *(const s16x8*)(As + (wr * 64 + m * 16 + (lane & 15)) * BK + ko);
        #pragma unroll
        for (int n = 0; n < 4; ++n)
            bfr[n] = *(const s16x8*)(Bs + (wc * 64 + n * 16 + (lane & 15)) * BK + ko);
        #pragma unroll
        for (int m = 0; m < 4; ++m)
            #pragma unroll
            for (int n = 0; n < 4; ++n)
                acc[m][n] = __builtin_amdgcn_mfma_f32_16x16x32_bf16(af[m], bfr[n], acc[m][n], 0, 0, 0);
        __syncthreads();
    }

    #pragma unroll
    for (int n = 0; n < 4; ++n) {
        int col = n0 + wc * 64 + n * 16 + (lane & 15);
        float bv = bias[col];
        float s = 0.f, q = 0.f;
        #pragma unroll
        for (int m = 0; m < 4; ++m) {
            int rbase = m0 + wr * 64 + m * 16 + (lane >> 4) * 4;
            #pragma unroll
            for (int r = 0; r < 4; ++r) {
                int row = rbase + r;
                if (row < N_NODES) {
                    float v = acc[m][n][r] + bv;
                    v = v > 0.f ? v : 0.f;
                    h[(size_t)row * D + col] = f2bf(v);
                    s += v;
                    q += v * v;
                }
            }
        }
        s += __shfl_xor(s, 16, 64);
        s += __shfl_xor(s, 32, 64);
        q += __shfl_xor(q, 16, 64);
        q += __shfl_xor(q, 32, 64);
        if (lane < 16) {
            atomicAdd(&colsum[col], s);
            atomicAdd(&colsumsq[col], q);
        }
    }
}

// ================= Fallback K7: BN apply =================
__global__ __launch_bounds__(256) void bn_apply(const short* __restrict__ h,
                                                float* __restrict__ out,
                                                const float* __restrict__ colsum,
                                                const float* __restrict__ colsumsq,
                                                const float* __restrict__ gamma,
                                                const float* __restrict__ beta) {
    __shared__ float s_scale[D], s_shift[D];
    for (int c = threadIdx.x; c < D; c += 256) {
        float mean = colsum[c] * (1.f / N_NODES);
        float var = colsumsq[c] * (1.f / N_NODES) - mean * mean;
        float rs = rsqrtf(var + BN_EPS);
        float sc = gamma[c] * rs;
        s_scale[c] = sc;
        s_shift[c] = beta[c] - mean * sc;
    }
    __syncthreads();
    const int total = N_NODES * D / 8;
    for (int i = blockIdx.x * 256 + threadIdx.x; i < total; i += gridDim.x * 256) {
        s16x8 hv = ((const s16x8*)h)[i];
        int c0 = (i * 8) & (D - 1);
        float4 o0, o1;
        o0.x = bf2f(hv[0]) * s_scale[c0]     + s_shift[c0];
        o0.y = bf2f(hv[1]) * s_scale[c0 + 1] + s_shift[c0 + 1];
        o0.z = bf2f(hv[2]) * s_scale[c0 + 2] + s_shift[c0 + 2];
        o0.w = bf2f(hv[3]) * s_scale[c0 + 3] + s_shift[c0 + 3];
        o1.x = bf2f(hv[4]) * s_scale[c0 + 4] + s_shift[c0 + 4];
        o1.y = bf2f(hv[5]) * s_scale[c0 + 5] + s_shift[c0 + 5];
        o1.z = bf2f(hv[6]) * s_scale[c0 + 6] + s_shift[c0 + 6];
        o1.w = bf2f(hv[7]) * s_scale[c0 + 7] + s_shift[c0 + 7];
        ((float4*)out)[i * 2]     = o0;
        ((float4*)out)[i * 2 + 1] = o1;
    }
}

extern "C" void kernel_launch(void* const* d_in, const int* in_sizes, int n_in,
                              void* d_out, int out_size, void* d_ws, size_t ws_size,
                              hipStream_t stream) {
    const float* x     = (const float*)d_in[0];
    const int*   src   = (const int*)d_in[1];
    const int*   dst   = (const int*)d_in[2];
    const float* W     = (const float*)d_in[3];
    const float* bias  = (const float*)d_in[4];
    const float* gamma = (const float*)d_in[5];
    const float* beta  = (const float*)d_in[6];
    float* out = (float*)d_out;

    char* ws = (char*)d_ws;
    size_t off = 0;
    float* colsum   = (float*)(ws + off); off += D * 4;
    float* colsumsq = (float*)(ws + off); off += D * 4;
    int*   rowstart = (int*)(ws + off);   off += (size_t)(N_NODES + 4) * 4;
    int*   cursor   = (int*)(ws + off);   off += (size_t)N_NODES * 4;
    int*   count    = (int*)(ws + off);   off += (size_t)ZCH * 16;
    int*   esrc     = (int*)(ws + off);   off += (size_t)N_EDGES * 4;
    off = (off + 255) & ~(size_t)255;
    short* Wb       = (short*)(ws + off); off += (size_t)D * D * 2;
    short* Xb       = (short*)(ws + off); off += (size_t)N_NODES * D * 2;
    short* Ab       = (short*)(ws + off); off += (size_t)MPAD * D * 2;
    short* hbuf     = (short*)(ws + off); off += (size_t)N_NODES * D * 2;

    convert_wx_zero<<<dim3((CONVCH + ZCH) / 256), dim3(256), 0, stream>>>(W, x, Wb, Xb, count);
    count_edges<<<dim3((N_EDGES / 8 + 255) / 256), dim3(256), 0, stream>>>(dst, count);
    scan_csr<<<dim3(1), dim3(1024), 0, stream>>>(count, rowstart, cursor, colsum, colsumsq);
    fill_edges<<<dim3((N_EDGES + 255) / 256), dim3(256), 0, stream>>>(src, dst, cursor, esrc);
    gather_bf16<<<dim3(MPAD / 4), dim3(256), 0, stream>>>(Xb, rowstart, esrc, Ab);

    // cooperative GEMM+BN; fall back to split kernels if unsupported
    const short* Ab_c = Ab;
    const short* Wb_c = Wb;
    const float* bias_c = bias;
    float* out_c = out;
    float* colsum_c = colsum;
    float* colsumsq_c = colsumsq;
    const float* gamma_c = gamma;
    const float* beta_c = beta;
    void* args[8] = { &Ab_c, &Wb_c, &bias_c, &out_c, &colsum_c, &colsumsq_c, &gamma_c, &beta_c };
    hipError_t err = hipLaunchCooperativeKernel((const void*)gemm_bn_fused,
                                                dim3(MPAD / BM, D / BNT), dim3(256),
                                                args, 0, stream);
    if (err != hipSuccess) {
        gemm_relu_stats<<<dim3(MPAD / BM, D / BNT), dim3(256), 0, stream>>>(Ab, Wb, bias, hbuf, colsum, colsumsq);
        bn_apply<<<dim3(2048), dim3(256), 0, stream>>>(hbuf, out, colsum, colsumsq, gamma, beta);
    }
}

// Round 12
// 108.219 us; speedup vs baseline: 1.6643x; 1.6643x over previous
//
#include <hip/hip_runtime.h>
#include <hip/hip_bf16.h>

#define N_NODES 20000
#define N_EDGES 150000
#define D 512
#define MPAD 20096   // 157 * 128
#define BN_EPS 1e-5f

typedef __attribute__((ext_vector_type(8))) short s16x8;
typedef __attribute__((ext_vector_type(4))) float f32x4;

__device__ __forceinline__ short f2bf(float f) {
    union { float f; unsigned u; } v; v.f = f;
    unsigned r = (v.u + 0x7fff + ((v.u >> 16) & 1)) >> 16;
    return (short)r;
}
__device__ __forceinline__ float bf2f(short b) {
    union { unsigned u; float f; } c;
    c.u = ((unsigned)(unsigned short)b) << 16;
    return c.f;
}
__device__ __forceinline__ s16x8 cvt8(const float* p) {
    float4 a = *(const float4*)p;
    float4 b = *(const float4*)(p + 4);
    s16x8 o;
    o[0] = f2bf(a.x); o[1] = f2bf(a.y); o[2] = f2bf(a.z); o[3] = f2bf(a.w);
    o[4] = f2bf(b.x); o[5] = f2bf(b.y); o[6] = f2bf(b.z); o[7] = f2bf(b.w);
    return o;
}

__device__ __forceinline__ void load_lds16(const short* g, short* l) {
    __builtin_amdgcn_global_load_lds((const __attribute__((address_space(1))) void*)g,
                                     (__attribute__((address_space(3))) void*)l, 16, 0, 0);
}

// ================= K1: W/X -> bf16 conversion + zero count array =================
#define WCH (D * D / 8)
#define XCH (N_NODES * D / 8)
#define CONVCH (WCH + XCH)
#define ZCH 5120
__global__ __launch_bounds__(256) void convert_wx_zero(const float* __restrict__ W,
                                                       const float* __restrict__ x,
                                                       short* __restrict__ Wb,
                                                       short* __restrict__ Xb,
                                                       int* __restrict__ count) {
    int c = blockIdx.x * 256 + threadIdx.x;
    if (c < WCH) {
        *(s16x8*)(Wb + (size_t)c * 8) = cvt8(W + (size_t)c * 8);
    } else if (c < CONVCH) {
        size_t idx = (size_t)(c - WCH) * 8;
        *(s16x8*)(Xb + idx) = cvt8(x + idx);
    } else {
        int z = c - CONVCH;
        if (z * 4 < N_NODES) *(int4*)(count + z * 4) = make_int4(0, 0, 0, 0);
    }
}

// ================= K2: count in-degrees =================
__global__ __launch_bounds__(256) void count_edges(const int* __restrict__ dst,
                                                   int* __restrict__ count) {
    int i = blockIdx.x * 256 + threadIdx.x;
    if (i * 8 < N_EDGES) {
        int4 a = *(const int4*)(dst + i * 8);
        int4 b = *(const int4*)(dst + i * 8 + 4);
        atomicAdd(&count[a.x], 1); atomicAdd(&count[a.y], 1);
        atomicAdd(&count[a.z], 1); atomicAdd(&count[a.w], 1);
        atomicAdd(&count[b.x], 1); atomicAdd(&count[b.y], 1);
        atomicAdd(&count[b.z], 1); atomicAdd(&count[b.w], 1);
    }
}

// ================= K3: scan (1 block, vectorized, reg prefix) =================
__global__ __launch_bounds__(1024) void scan_csr(const int* __restrict__ count,
                                                 int* __restrict__ rowstart,
                                                 int* __restrict__ cursor,
                                                 float* __restrict__ colsum,
                                                 float* __restrict__ colsumsq) {
    __shared__ int partial[1024];
    int t = threadIdx.x;
    if (t < D) colsum[t] = 0.f;
    else if (t < 2 * D) colsumsq[t - D] = 0.f;

    int v[20];
    int s = 0;
    if (t < 1000) {
        const int4* p = (const int4*)(count + t * 20);
        #pragma unroll
        for (int j = 0; j < 5; ++j) {
            int4 q = p[j];
            v[j * 4 + 0] = q.x; v[j * 4 + 1] = q.y;
            v[j * 4 + 2] = q.z; v[j * 4 + 3] = q.w;
        }
        #pragma unroll
        for (int j = 0; j < 20; ++j) s += v[j];
    }
    partial[t] = s;
    __syncthreads();
    for (int off = 1; off < 1024; off <<= 1) {
        int p2 = (t >= off) ? partial[t - off] : 0;
        __syncthreads();
        partial[t] += p2;
        __syncthreads();
    }
    if (t < 1000) {
        int run = (t == 0) ? 0 : partial[t - 1];
        int rs[20];
        #pragma unroll
        for (int j = 0; j < 20; ++j) { rs[j] = run; run += v[j]; }
        int4* rp = (int4*)(rowstart + t * 20);
        int4* cp = (int4*)(cursor + t * 20);
        #pragma unroll
        for (int j = 0; j < 5; ++j) {
            int4 q = make_int4(rs[j * 4], rs[j * 4 + 1], rs[j * 4 + 2], rs[j * 4 + 3]);
            rp[j] = q;
            cp[j] = q;
        }
    }
    if (t == 1023) rowstart[N_NODES] = partial[1023];
}

// ================= K4: fill sorted edge list =================
__global__ __launch_bounds__(256) void fill_edges(const int* __restrict__ src,
                                                  const int* __restrict__ dst,
                                                  int* __restrict__ cursor,
                                                  int* __restrict__ esrc) {
    int i = blockIdx.x * 256 + threadIdx.x;
    if (i < N_EDGES) {
        int p = atomicAdd(&cursor[dst[i]], 1);
        esrc[p] = src[i];
    }
}

// ================= K5: gather, 4 independent accumulator banks =================
__global__ __launch_bounds__(256) void gather_bf16(const short* __restrict__ Xb,
                                                   const int* __restrict__ rowstart,
                                                   const int* __restrict__ esrc,
                                                   short* __restrict__ Ab) {
    int node = (blockIdx.x * 256 + threadIdx.x) >> 6;
    int lane = threadIdx.x & 63;
    if (node >= MPAD) return;
    size_t cb = (size_t)lane * 8;
    s16x8 o;
    if (node >= N_NODES) {
        o = (s16x8)0;
    } else {
        int e0 = rowstart[node], e1 = rowstart[node + 1];
        if (e0 == e1) {
            o = *(const s16x8*)(Xb + (size_t)node * D + cb);
        } else {
            float a0[8] = {}, a1[8] = {}, a2[8] = {}, a3[8] = {};
            int e = e0;
            for (; e + 3 < e1; e += 4) {
                int s0 = esrc[e], s1 = esrc[e + 1], s2 = esrc[e + 2], s3 = esrc[e + 3];
                s16x8 v0 = *(const s16x8*)(Xb + (size_t)s0 * D + cb);
                s16x8 v1 = *(const s16x8*)(Xb + (size_t)s1 * D + cb);
                s16x8 v2 = *(const s16x8*)(Xb + (size_t)s2 * D + cb);
                s16x8 v3 = *(const s16x8*)(Xb + (size_t)s3 * D + cb);
                #pragma unroll
                for (int i = 0; i < 8; ++i) a0[i] += bf2f(v0[i]);
                #pragma unroll
                for (int i = 0; i < 8; ++i) a1[i] += bf2f(v1[i]);
                #pragma unroll
                for (int i = 0; i < 8; ++i) a2[i] += bf2f(v2[i]);
                #pragma unroll
                for (int i = 0; i < 8; ++i) a3[i] += bf2f(v3[i]);
            }
            if (e < e1) {
                s16x8 v0 = *(const s16x8*)(Xb + (size_t)esrc[e] * D + cb);
                #pragma unroll
                for (int i = 0; i < 8; ++i) a0[i] += bf2f(v0[i]);
            }
            if (e + 1 < e1) {
                s16x8 v1 = *(const s16x8*)(Xb + (size_t)esrc[e + 1] * D + cb);
                #pragma unroll
                for (int i = 0; i < 8; ++i) a1[i] += bf2f(v1[i]);
            }
            if (e + 2 < e1) {
                s16x8 v2 = *(const s16x8*)(Xb + (size_t)esrc[e + 2] * D + cb);
                #pragma unroll
                for (int i = 0; i < 8; ++i) a2[i] += bf2f(v2[i]);
            }
            #pragma unroll
            for (int i = 0; i < 8; ++i) o[i] = f2bf((a0[i] + a1[i]) + (a2[i] + a3[i]));
        }
    }
    *(s16x8*)(Ab + (size_t)node * D + cb) = o;
}

// ================= K6: GEMM h = relu(A @ W^T + b) bf16, fused stats =================
// 128x128 tile, 4 waves, XCD-aware 1D grid: blocks {b, b+8, b+16, b+24} share an
// A-tile and land on the same XCD (b%8 equal) -> A re-reads become L2 hits.
#define BM 128
#define BNT 128
#define BK 32
#define MTILES (MPAD / BM)          // 157
#define GEMM_BLOCKS 640             // ceil(157/8)=20 chunks * 32

__global__ __launch_bounds__(256) void gemm_relu_stats(const short* __restrict__ A,
                                                       const short* __restrict__ B,
                                                       const float* __restrict__ bias,
                                                       short* __restrict__ h,
                                                       float* __restrict__ colsum,
                                                       float* __restrict__ colsumsq) {
    __shared__ short As[BM * BK];
    __shared__ short Bs[BNT * BK];
    int b = blockIdx.x;
    int sC = b >> 5, k = b & 31;
    int mt = sC * 8 + (k & 7);
    int nt = k >> 3;
    if (mt >= MTILES) return;
    int m0 = mt * BM;
    int n0 = nt * BNT;

    int tid = threadIdx.x;
    int lane = tid & 63;
    int wave = tid >> 6;
    int wr = wave >> 1, wc = wave & 1;

    f32x4 acc[4][4] = {};

    int srow = lane >> 2;
    int scol = (lane & 3) * 8;
    const short* Ag = A + (size_t)(m0 + wave * 32 + srow) * D + scol;
    const short* Bg = B + (size_t)(n0 + wave * 32 + srow) * D + scol;
    short* Asl = As + wave * 1024;
    short* Bsl = Bs + wave * 1024;

    for (int kt = 0; kt < D; kt += BK) {
        #pragma unroll
        for (int j = 0; j < 2; ++j) {
            load_lds16(Ag + (size_t)j * 16 * D + kt, Asl + j * 512);
            load_lds16(Bg + (size_t)j * 16 * D + kt, Bsl + j * 512);
        }
        __syncthreads();
        s16x8 af[4], bfr[4];
        int ko = (lane >> 4) * 8;
        #pragma unroll
        for (int m = 0; m < 4; ++m)
            af[m] = *(const s16x8*)(As + (wr * 64 + m * 16 + (lane & 15)) * BK + ko);
        #pragma unroll
        for (int n = 0; n < 4; ++n)
            bfr[n] = *(const s16x8*)(Bs + (wc * 64 + n * 16 + (lane & 15)) * BK + ko);
        #pragma unroll
        for (int m = 0; m < 4; ++m)
            #pragma unroll
            for (int n = 0; n < 4; ++n)
                acc[m][n] = __builtin_amdgcn_mfma_f32_16x16x32_bf16(af[m], bfr[n], acc[m][n], 0, 0, 0);
        __syncthreads();
    }

    #pragma unroll
    for (int n = 0; n < 4; ++n) {
        int col = n0 + wc * 64 + n * 16 + (lane & 15);
        float bv = bias[col];
        float s = 0.f, q = 0.f;
        #pragma unroll
        for (int m = 0; m < 4; ++m) {
            int rbase = m0 + wr * 64 + m * 16 + (lane >> 4) * 4;
            #pragma unroll
            for (int r = 0; r < 4; ++r) {
                int row = rbase + r;
                if (row < N_NODES) {
                    float v = acc[m][n][r] + bv;
                    v = v > 0.f ? v : 0.f;
                    h[(size_t)row * D + col] = f2bf(v);
                    s += v;
                    q += v * v;
                }
            }
        }
        s += __shfl_xor(s, 16, 64);
        s += __shfl_xor(s, 32, 64);
        q += __shfl_xor(q, 16, 64);
        q += __shfl_xor(q, 32, 64);
        if (lane < 16) {
            atomicAdd(&colsum[col], s);
            atomicAdd(&colsumsq[col], q);
        }
    }
}

// ================= K7: BN apply =================
__global__ __launch_bounds__(256) void bn_apply(const short* __restrict__ h,
                                                float* __restrict__ out,
                                                const float* __restrict__ colsum,
                                                const float* __restrict__ colsumsq,
                                                const float* __restrict__ gamma,
                                                const float* __restrict__ beta) {
    __shared__ float s_scale[D], s_shift[D];
    for (int c = threadIdx.x; c < D; c += 256) {
        float mean = colsum[c] * (1.f / N_NODES);
        float var = colsumsq[c] * (1.f / N_NODES) - mean * mean;
        float rs = rsqrtf(var + BN_EPS);
        float sc = gamma[c] * rs;
        s_scale[c] = sc;
        s_shift[c] = beta[c] - mean * sc;
    }
    __syncthreads();
    const int total = N_NODES * D / 8;
    for (int i = blockIdx.x * 256 + threadIdx.x; i < total; i += gridDim.x * 256) {
        s16x8 hv = ((const s16x8*)h)[i];
        int c0 = (i * 8) & (D - 1);
        float4 o0, o1;
        o0.x = bf2f(hv[0]) * s_scale[c0]     + s_shift[c0];
        o0.y = bf2f(hv[1]) * s_scale[c0 + 1] + s_shift[c0 + 1];
        o0.z = bf2f(hv[2]) * s_scale[c0 + 2] + s_shift[c0 + 2];
        o0.w = bf2f(hv[3]) * s_scale[c0 + 3] + s_shift[c0 + 3];
        o1.x = bf2f(hv[4]) * s_scale[c0 + 4] + s_shift[c0 + 4];
        o1.y = bf2f(hv[5]) * s_scale[c0 + 5] + s_shift[c0 + 5];
        o1.z = bf2f(hv[6]) * s_scale[c0 + 6] + s_shift[c0 + 6];
        o1.w = bf2f(hv[7]) * s_scale[c0 + 7] + s_shift[c0 + 7];
        ((float4*)out)[i * 2]     = o0;
        ((float4*)out)[i * 2 + 1] = o1;
    }
}

extern "C" void kernel_launch(void* const* d_in, const int* in_sizes, int n_in,
                              void* d_out, int out_size, void* d_ws, size_t ws_size,
                              hipStream_t stream) {
    const float* x     = (const float*)d_in[0];
    const int*   src   = (const int*)d_in[1];
    const int*   dst   = (const int*)d_in[2];
    const float* W     = (const float*)d_in[3];
    const float* bias  = (const float*)d_in[4];
    const float* gamma = (const float*)d_in[5];
    const float* beta  = (const float*)d_in[6];
    float* out = (float*)d_out;

    char* ws = (char*)d_ws;
    size_t off = 0;
    float* colsum   = (float*)(ws + off); off += D * 4;
    float* colsumsq = (float*)(ws + off); off += D * 4;
    int*   rowstart = (int*)(ws + off);   off += (size_t)(N_NODES + 4) * 4;
    int*   cursor   = (int*)(ws + off);   off += (size_t)N_NODES * 4;
    int*   count    = (int*)(ws + off);   off += (size_t)ZCH * 16;
    int*   esrc     = (int*)(ws + off);   off += (size_t)N_EDGES * 4;
    off = (off + 255) & ~(size_t)255;
    short* Wb       = (short*)(ws + off); off += (size_t)D * D * 2;
    short* Xb       = (short*)(ws + off); off += (size_t)N_NODES * D * 2;
    short* Ab       = (short*)(ws + off); off += (size_t)MPAD * D * 2;
    short* hbuf     = (short*)(ws + off); off += (size_t)N_NODES * D * 2;

    convert_wx_zero<<<dim3((CONVCH + ZCH) / 256), dim3(256), 0, stream>>>(W, x, Wb, Xb, count);
    count_edges<<<dim3((N_EDGES / 8 + 255) / 256), dim3(256), 0, stream>>>(dst, count);
    scan_csr<<<dim3(1), dim3(1024), 0, stream>>>(count, rowstart, cursor, colsum, colsumsq);
    fill_edges<<<dim3((N_EDGES + 255) / 256), dim3(256), 0, stream>>>(src, dst, cursor, esrc);
    gather_bf16<<<dim3(MPAD / 4), dim3(256), 0, stream>>>(Xb, rowstart, esrc, Ab);
    gemm_relu_stats<<<dim3(GEMM_BLOCKS), dim3(256), 0, stream>>>(Ab, Wb, bias, hbuf, colsum, colsumsq);
    bn_apply<<<dim3(2048), dim3(256), 0, stream>>>(hbuf, out, colsum, colsumsq, gamma, beta);
}